// Round 3
// baseline (57.288 us; speedup 1.0000x reference)
//
#include <hip/hip_runtime.h>
#include <math.h>

#define DIM 9
#define SINE_AMP 0.1f
#define NOISE_STD 0.003f

typedef float f32x4 __attribute__((ext_vector_type(4)));
typedef float f32x2 __attribute__((ext_vector_type(2)));

// ---------------------------------------------------------------------------
// Kernel 1: one wave per (b, d) chain.
// Computes rad[b,l,d] with exact f32 reference semantics and
// base[b,l,d] = frac( upp * sum_{l' < l} rad[b,l',d] ) via a double scan.
// uv is folded in: unvoiced frames store rad=base=0 (sin(0)=0 == sine*uv).
// Also emits namp[b,l] = uv ? 0.003 : 0.1/3 (per-frame noise amplitude).
// ---------------------------------------------------------------------------
__global__ void __launch_bounds__(64)
phase_scan_kernel(const float* __restrict__ f0,
                  const float* __restrict__ rand_ini,
                  f32x2* __restrict__ rb_out,        // (B,L,DIM) {rad, base}
                  float* __restrict__ namp_out,      // (B,L)
                  int B, int L, int upp)
{
    const int bd   = blockIdx.x;        // b*DIM + d
    const int b    = bd / DIM;
    const int d    = bd - b * DIM;
    const int lane = threadIdx.x;       // 0..63
    const float hf = (float)(d + 1);
    const float ri = (d == 0) ? 0.0f : rand_ini[b * DIM + d];

    double carry = 0.0;
    for (int c0 = 0; c0 < L; c0 += 64) {
        const int l = c0 + lane;
        float r = 0.0f, fv = 0.0f;
        if (l < L) {
            fv = f0[b * L + l];
            // reference: f0_buf = f0 * h (f32); rad = (f0_buf / SR) % 1.0 (f32)
            r = fmodf(fv * hf / 48000.0f, 1.0f);
            if (l == 0) r += ri;        // rand_ini added at frame 0 (f32 add)
        }
        const double rd = (double)r;
        double inc = rd;
        // wave-64 inclusive scan in double
        #pragma unroll
        for (int off = 1; off < 64; off <<= 1) {
            double t = __shfl_up(inc, off, 64);
            if (lane >= off) inc += t;
        }
        if (l < L) {
            const double excl = carry + (inc - rd);   // exclusive prefix
            double bf = excl * (double)upp;
            bf -= floor(bf);                          // frac in double
            const bool voiced = fv > 0.0f;
            f32x2 rbv;
            rbv.x = voiced ? r : 0.0f;
            rbv.y = voiced ? (float)bf : 0.0f;
            rb_out[(b * L + l) * DIM + d] = rbv;
            if (d == 0)
                namp_out[b * L + l] = voiced ? NOISE_STD : (SINE_AMP / 3.0f);
        }
        carry += __shfl(inc, 63, 64);
    }
}

// ---------------------------------------------------------------------------
// Kernel 2: fully parallel sample generation, pure streaming.
//   sine = fma(sin(frac(base + (j+1)*rad)), 0.1, namp*nz)   (uv pre-folded)
//   noise = namp*nz
// plus a separate fully-coalesced loop writing uv (B, Lo).
// ---------------------------------------------------------------------------
template <int UPP>
__global__ void __launch_bounds__(256)
sine_gen_kernel(const float* __restrict__ f0,
                const float* __restrict__ noise_randn,
                const f32x2* __restrict__ rb,
                const float* __restrict__ namp_arr,
                float* __restrict__ out_sine,
                float* __restrict__ out_uv,
                float* __restrict__ out_noise,
                int L, int Lo, int upp)
{
    const unsigned UPPD = (UPP > 0) ? (unsigned)UPP : 1u;   // compile-time divisor
    const unsigned uppv = (UPP > 0) ? (unsigned)UPP : (unsigned)upp;

    const int b   = blockIdx.y;
    const int LoD = Lo * DIM;
    const unsigned n4 = (unsigned)LoD >> 2;
    const long long boff = (long long)b * LoD;

    const f32x4* __restrict__ nz_b    = (const f32x4*)(noise_randn + boff);
    f32x4* __restrict__       sine_b  = (f32x4*)(out_sine + boff);
    f32x4* __restrict__       noise_b = (f32x4*)(out_noise + boff);
    const float*  __restrict__ f0_b   = f0 + b * L;
    const float*  __restrict__ namp_b = namp_arr + b * L;
    const f32x2* __restrict__  rb_b   = rb + b * L * DIM;

    const unsigned tid    = blockIdx.x * blockDim.x + threadIdx.x;
    const unsigned stride = gridDim.x * blockDim.x;

    for (unsigned i4 = tid; i4 < n4; i4 += stride) {
        const unsigned i0 = i4 << 2;
        const f32x4 nr = __builtin_nontemporal_load(nz_b + i4);
        f32x4 sv, nv;
        #pragma unroll
        for (int k = 0; k < 4; ++k) {
            const unsigned rem = i0 + (unsigned)k;
            const unsigned o = rem / 9u;            // const divisor -> magic mul
            const unsigned d = rem - o * 9u;
            unsigned l, j;
            if (UPP > 0) { l = o / UPPD; j = o - l * UPPD; }
            else         { l = o / (unsigned)upp; j = o - l * (unsigned)upp; }
            const f32x2 rbv = rb_b[l * 9u + d];     // {rad, base}, L1-hit
            float ph = fmaf((float)(j + 1u), rbv.x, rbv.y);
            ph -= floorf(ph);                        // revolutions in [0,1)
            float s;
            asm("v_sin_f32 %0, %1" : "=v"(s) : "v"(ph));  // sin(2*pi*x)
            const float nzv = namp_b[l] * nr[k];
            nv[k] = nzv;
            sv[k] = fmaf(s, SINE_AMP, nzv);
        }
        __builtin_nontemporal_store(sv, sine_b + i4);
        __builtin_nontemporal_store(nv, noise_b + i4);
    }

    // uv output: (B, Lo), fully coalesced float4 stores
    f32x4* __restrict__ uv_b4 = (f32x4*)(out_uv + (long long)b * Lo);
    const unsigned nu4 = (unsigned)Lo >> 2;
    for (unsigned u4 = tid; u4 < nu4; u4 += stride) {
        const unsigned o0 = u4 << 2;
        f32x4 uvv;
        #pragma unroll
        for (int k = 0; k < 4; ++k) {
            const unsigned o = o0 + (unsigned)k;
            const unsigned l = o / uppv;
            uvv[k] = (f0_b[l] > 0.0f) ? 1.0f : 0.0f;
        }
        __builtin_nontemporal_store(uvv, uv_b4 + u4);
    }

    // tails (not hit for upp=512; cheap insurance for odd shapes)
    if (blockIdx.x == 0 && threadIdx.x < (unsigned)(LoD & 3)) {
        const unsigned rem = (n4 << 2) + threadIdx.x;
        const unsigned o = rem / 9u;
        const unsigned d = rem - o * 9u;
        const unsigned l = o / uppv;
        const unsigned j = o - l * uppv;
        const f32x2 rbv = rb_b[l * 9u + d];
        float ph = fmaf((float)(j + 1u), rbv.x, rbv.y);
        ph -= floorf(ph);
        float s;
        asm("v_sin_f32 %0, %1" : "=v"(s) : "v"(ph));
        const float nzv = namp_b[l] * ((const float*)nz_b)[rem];
        ((float*)noise_b)[rem] = nzv;
        ((float*)sine_b)[rem]  = fmaf(s, SINE_AMP, nzv);
    }
    if (blockIdx.x == 0 && threadIdx.x < (unsigned)(Lo & 3)) {
        const unsigned o = (nu4 << 2) + threadIdx.x;
        const unsigned l = o / uppv;
        ((float*)uv_b4)[o] = (f0_b[l] > 0.0f) ? 1.0f : 0.0f;
    }
}

extern "C" void kernel_launch(void* const* d_in, const int* in_sizes, int n_in,
                              void* d_out, int out_size, void* d_ws, size_t ws_size,
                              hipStream_t stream)
{
    const float* f0       = (const float*)d_in[0];
    const float* rand_ini = (const float*)d_in[1];
    const float* noise    = (const float*)d_in[2];
    const int B  = in_sizes[1] / DIM;        // rand_ini is (B, DIM)
    const int L  = in_sizes[0] / B;          // f0 is (B, L)
    const int Lo = in_sizes[2] / (B * DIM);  // noise_randn is (B, Lo, DIM)
    const int upp = Lo / L;

    float* out       = (float*)d_out;
    float* out_sine  = out;
    float* out_uv    = out_sine + (long long)B * Lo * DIM;
    float* out_noise = out_uv + (long long)B * Lo;

    f32x2* rb_ws   = (f32x2*)d_ws;
    float* namp_ws = (float*)(rb_ws + (size_t)B * L * DIM);

    phase_scan_kernel<<<dim3(B * DIM), dim3(64), 0, stream>>>(
        f0, rand_ini, rb_ws, namp_ws, B, L, upp);

    const int n4 = (Lo * DIM) >> 2;
    int bx = (n4 + 255) / 256;
    if (bx > 1024) bx = 1024;
    dim3 grid(bx, B);
    if (upp == 512) {
        sine_gen_kernel<512><<<grid, dim3(256), 0, stream>>>(
            f0, noise, rb_ws, namp_ws, out_sine, out_uv, out_noise, L, Lo, upp);
    } else {
        sine_gen_kernel<0><<<grid, dim3(256), 0, stream>>>(
            f0, noise, rb_ws, namp_ws, out_sine, out_uv, out_noise, L, Lo, upp);
    }
}

// Round 4
// 44.760 us; speedup vs baseline: 1.2799x; 1.2799x over previous
//
#include <hip/hip_runtime.h>
#include <math.h>

#define DIM 9
#define SINE_AMP 0.1f
#define NOISE_STD 0.003f

typedef float f32x4 __attribute__((ext_vector_type(4)));
typedef float f32x2 __attribute__((ext_vector_type(2)));

// ---------------------------------------------------------------------------
// Kernel 1: one 1024-thread block per (b, d) chain — single-pass block scan.
// rad[b,l,d] with exact f32 reference semantics;
// base[b,l,d] = frac( upp * sum_{l' < l} rad[b,l',d] ) via a double scan.
// uv folded in: unvoiced frames store rad=base=0 (sin(0)=0 == sine*uv).
// Also emits namp[b,l] = uv ? 0.003 : 0.1/3.
// ---------------------------------------------------------------------------
__global__ void __launch_bounds__(1024)
phase_scan_kernel(const float* __restrict__ f0,
                  const float* __restrict__ rand_ini,
                  f32x2* __restrict__ rb_out,        // (B,L,DIM) {rad, base}
                  float* __restrict__ namp_out,      // (B,L)
                  int B, int L, int upp)
{
    const int bd   = blockIdx.x;        // b*DIM + d
    const int b    = bd / DIM;
    const int d    = bd - b * DIM;
    const int tid  = threadIdx.x;
    const int lane = tid & 63;
    const int wid  = tid >> 6;          // 0..15
    const float hf = (float)(d + 1);
    const float ri = (d == 0) ? 0.0f : rand_ini[b * DIM + d];

    __shared__ double partials[16];
    __shared__ double wave_off[17];     // [16] = chunk total

    double carry = 0.0;
    for (int c0 = 0; c0 < L; c0 += 1024) {
        const int l = c0 + tid;
        float r = 0.0f, fv = 0.0f;
        if (l < L) {
            fv = f0[b * L + l];
            // reference: f0_buf = f0 * h (f32); rad = (f0_buf / SR) % 1.0 (f32)
            r = fmodf(fv * hf / 48000.0f, 1.0f);
            if (l == 0) r += ri;        // rand_ini added at frame 0 (f32 add)
        }
        const double rd = (double)r;
        double inc = rd;
        // wave-64 inclusive scan in double
        #pragma unroll
        for (int off = 1; off < 64; off <<= 1) {
            double t = __shfl_up(inc, off, 64);
            if (lane >= off) inc += t;
        }
        if (lane == 63) partials[wid] = inc;
        __syncthreads();
        if (tid == 0) {
            double run = 0.0;
            #pragma unroll
            for (int w = 0; w < 16; ++w) { wave_off[w] = run; run += partials[w]; }
            wave_off[16] = run;
        }
        __syncthreads();
        if (l < L) {
            const double excl = carry + wave_off[wid] + (inc - rd);
            double bf = excl * (double)upp;
            bf -= floor(bf);                          // frac in double
            const bool voiced = fv > 0.0f;
            f32x2 rbv;
            rbv.x = voiced ? r : 0.0f;
            rbv.y = voiced ? (float)bf : 0.0f;
            rb_out[(b * L + l) * DIM + d] = rbv;
            if (d == 0)
                namp_out[b * L + l] = voiced ? NOISE_STD : (SINE_AMP / 3.0f);
        }
        carry += wave_off[16];
        __syncthreads();   // partials reused next chunk
    }
}

// ---------------------------------------------------------------------------
// Kernel 2: fully parallel sample generation, pure streaming (PLAIN ld/st —
// nontemporal hints measurably hurt store BW on gfx950: 53.8 -> 57.3 us).
//   sine = fma(sin(frac(base + (j+1)*rad)), 0.1, namp*nz)   (uv pre-folded)
//   noise = namp*nz
// plus a separate fully-coalesced loop writing uv (B, Lo).
// ---------------------------------------------------------------------------
template <int UPP>
__global__ void __launch_bounds__(256)
sine_gen_kernel(const float* __restrict__ f0,
                const float* __restrict__ noise_randn,
                const f32x2* __restrict__ rb,
                const float* __restrict__ namp_arr,
                float* __restrict__ out_sine,
                float* __restrict__ out_uv,
                float* __restrict__ out_noise,
                int L, int Lo, int upp)
{
    const unsigned UPPD = (UPP > 0) ? (unsigned)UPP : 1u;   // compile-time divisor
    const unsigned uppv = (UPP > 0) ? (unsigned)UPP : (unsigned)upp;

    const int b   = blockIdx.y;
    const int LoD = Lo * DIM;
    const unsigned n4 = (unsigned)LoD >> 2;
    const long long boff = (long long)b * LoD;

    const f32x4* __restrict__ nz_b    = (const f32x4*)(noise_randn + boff);
    f32x4* __restrict__       sine_b  = (f32x4*)(out_sine + boff);
    f32x4* __restrict__       noise_b = (f32x4*)(out_noise + boff);
    const float*  __restrict__ f0_b   = f0 + b * L;
    const float*  __restrict__ namp_b = namp_arr + b * L;
    const f32x2* __restrict__  rb_b   = rb + b * L * DIM;

    const unsigned tid    = blockIdx.x * blockDim.x + threadIdx.x;
    const unsigned stride = gridDim.x * blockDim.x;

    for (unsigned i4 = tid; i4 < n4; i4 += stride) {
        const unsigned i0 = i4 << 2;
        const f32x4 nr = nz_b[i4];
        f32x4 sv, nv;
        #pragma unroll
        for (int k = 0; k < 4; ++k) {
            const unsigned rem = i0 + (unsigned)k;
            const unsigned o = rem / 9u;            // const divisor -> magic mul
            const unsigned d = rem - o * 9u;
            unsigned l, j;
            if (UPP > 0) { l = o / UPPD; j = o - l * UPPD; }
            else         { l = o / (unsigned)upp; j = o - l * (unsigned)upp; }
            const f32x2 rbv = rb_b[l * 9u + d];     // {rad, base}, L1/L2-hit
            float ph = fmaf((float)(j + 1u), rbv.x, rbv.y);
            ph -= floorf(ph);                        // revolutions in [0,1)
            float s;
            asm("v_sin_f32 %0, %1" : "=v"(s) : "v"(ph));  // sin(2*pi*x)
            const float nzv = namp_b[l] * nr[k];
            nv[k] = nzv;
            sv[k] = fmaf(s, SINE_AMP, nzv);
        }
        sine_b[i4]  = sv;
        noise_b[i4] = nv;
    }

    // uv output: (B, Lo), fully coalesced float4 stores
    f32x4* __restrict__ uv_b4 = (f32x4*)(out_uv + (long long)b * Lo);
    const unsigned nu4 = (unsigned)Lo >> 2;
    for (unsigned u4 = tid; u4 < nu4; u4 += stride) {
        const unsigned o0 = u4 << 2;
        f32x4 uvv;
        #pragma unroll
        for (int k = 0; k < 4; ++k) {
            const unsigned o = o0 + (unsigned)k;
            const unsigned l = o / uppv;
            uvv[k] = (f0_b[l] > 0.0f) ? 1.0f : 0.0f;
        }
        uv_b4[u4] = uvv;
    }

    // tails (not hit for upp=512; cheap insurance for odd shapes)
    if (blockIdx.x == 0 && threadIdx.x < (unsigned)(LoD & 3)) {
        const unsigned rem = (n4 << 2) + threadIdx.x;
        const unsigned o = rem / 9u;
        const unsigned d = rem - o * 9u;
        const unsigned l = o / uppv;
        const unsigned j = o - l * uppv;
        const f32x2 rbv = rb_b[l * 9u + d];
        float ph = fmaf((float)(j + 1u), rbv.x, rbv.y);
        ph -= floorf(ph);
        float s;
        asm("v_sin_f32 %0, %1" : "=v"(s) : "v"(ph));
        const float nzv = namp_b[l] * ((const float*)nz_b)[rem];
        ((float*)noise_b)[rem] = nzv;
        ((float*)sine_b)[rem]  = fmaf(s, SINE_AMP, nzv);
    }
    if (blockIdx.x == 0 && threadIdx.x < (unsigned)(Lo & 3)) {
        const unsigned o = (nu4 << 2) + threadIdx.x;
        const unsigned l = o / uppv;
        ((float*)uv_b4)[o] = (f0_b[l] > 0.0f) ? 1.0f : 0.0f;
    }
}

extern "C" void kernel_launch(void* const* d_in, const int* in_sizes, int n_in,
                              void* d_out, int out_size, void* d_ws, size_t ws_size,
                              hipStream_t stream)
{
    const float* f0       = (const float*)d_in[0];
    const float* rand_ini = (const float*)d_in[1];
    const float* noise    = (const float*)d_in[2];
    const int B  = in_sizes[1] / DIM;        // rand_ini is (B, DIM)
    const int L  = in_sizes[0] / B;          // f0 is (B, L)
    const int Lo = in_sizes[2] / (B * DIM);  // noise_randn is (B, Lo, DIM)
    const int upp = Lo / L;

    float* out       = (float*)d_out;
    float* out_sine  = out;
    float* out_uv    = out_sine + (long long)B * Lo * DIM;
    float* out_noise = out_uv + (long long)B * Lo;

    f32x2* rb_ws   = (f32x2*)d_ws;
    float* namp_ws = (float*)(rb_ws + (size_t)B * L * DIM);

    phase_scan_kernel<<<dim3(B * DIM), dim3(1024), 0, stream>>>(
        f0, rand_ini, rb_ws, namp_ws, B, L, upp);

    const int n4 = (Lo * DIM) >> 2;
    int bx = (n4 + 255) / 256;
    if (bx > 1024) bx = 1024;
    dim3 grid(bx, B);
    if (upp == 512) {
        sine_gen_kernel<512><<<grid, dim3(256), 0, stream>>>(
            f0, noise, rb_ws, namp_ws, out_sine, out_uv, out_noise, L, Lo, upp);
    } else {
        sine_gen_kernel<0><<<grid, dim3(256), 0, stream>>>(
            f0, noise, rb_ws, namp_ws, out_sine, out_uv, out_noise, L, Lo, upp);
    }
}

// Round 5
// 44.603 us; speedup vs baseline: 1.2844x; 1.0035x over previous
//
#include <hip/hip_runtime.h>
#include <math.h>

#define DIM 9
#define SINE_AMP 0.1f
#define NOISE_STD 0.003f

typedef float f32x4 __attribute__((ext_vector_type(4)));
typedef float f32x2 __attribute__((ext_vector_type(2)));

// ---------------------------------------------------------------------------
// Kernel 1: one 1024-thread block per (b, d) chain — single-pass block scan.
// rad[b,l,d] with exact f32 reference semantics;
// base[b,l,d] = frac( upp * sum_{l' < l} rad[b,l',d] ) via a double scan.
// uv folded in: unvoiced frames store rad=base=0 (sin(0)=0 == sine*uv), and
// voiced frames always have rad>0 (f0*h/48000 < 0.075, plus ri>=0 at l=0),
// so downstream voiced-ness is recovered as (rad > 0) — no namp table needed.
// ---------------------------------------------------------------------------
__global__ void __launch_bounds__(1024)
phase_scan_kernel(const float* __restrict__ f0,
                  const float* __restrict__ rand_ini,
                  f32x2* __restrict__ rb_out,        // (B,L,DIM) {rad, base}
                  int B, int L, int upp)
{
    const int bd   = blockIdx.x;        // b*DIM + d
    const int b    = bd / DIM;
    const int d    = bd - b * DIM;
    const int tid  = threadIdx.x;
    const int lane = tid & 63;
    const int wid  = tid >> 6;          // 0..15
    const float hf = (float)(d + 1);
    const float ri = (d == 0) ? 0.0f : rand_ini[b * DIM + d];

    __shared__ double partials[16];
    __shared__ double wave_off[17];     // [16] = chunk total

    double carry = 0.0;
    for (int c0 = 0; c0 < L; c0 += 1024) {
        const int l = c0 + tid;
        float r = 0.0f, fv = 0.0f;
        if (l < L) {
            fv = f0[b * L + l];
            // reference: f0_buf = f0 * h (f32); rad = (f0_buf / SR) % 1.0 (f32)
            r = fmodf(fv * hf / 48000.0f, 1.0f);
            if (l == 0) r += ri;        // rand_ini added at frame 0 (f32 add)
        }
        const double rd = (double)r;
        double inc = rd;
        // wave-64 inclusive scan in double
        #pragma unroll
        for (int off = 1; off < 64; off <<= 1) {
            double t = __shfl_up(inc, off, 64);
            if (lane >= off) inc += t;
        }
        if (lane == 63) partials[wid] = inc;
        __syncthreads();
        if (tid == 0) {
            double run = 0.0;
            #pragma unroll
            for (int w = 0; w < 16; ++w) { wave_off[w] = run; run += partials[w]; }
            wave_off[16] = run;
        }
        __syncthreads();
        if (l < L) {
            const double excl = carry + wave_off[wid] + (inc - rd);
            double bf = excl * (double)upp;
            bf -= floor(bf);                          // frac in double
            const bool voiced = fv > 0.0f;
            f32x2 rbv;
            rbv.x = voiced ? r : 0.0f;
            rbv.y = voiced ? (float)bf : 0.0f;
            rb_out[(b * L + l) * DIM + d] = rbv;
        }
        carry += wave_off[16];
        __syncthreads();   // partials reused next chunk
    }
}

// ---------------------------------------------------------------------------
// Kernel 2: fully parallel sample generation, pure streaming (PLAIN ld/st —
// nontemporal hints measurably hurt store BW on gfx950: 53.8 -> 57.3 us).
// Per float4: 1 magic-div for (o,d), incremental wrap after; namp derived
// from rad>0 (no table). 7 VMEM / iter (was 11).
//   sine = fma(sin(frac(base + (j+1)*rad)), 0.1, namp*nz)   (uv pre-folded)
//   noise = namp*nz
// ---------------------------------------------------------------------------
template <int UPP>
__global__ void __launch_bounds__(256)
sine_gen_kernel(const float* __restrict__ f0,
                const float* __restrict__ noise_randn,
                const f32x2* __restrict__ rb,
                float* __restrict__ out_sine,
                float* __restrict__ out_uv,
                float* __restrict__ out_noise,
                int L, int Lo, int upp)
{
    const unsigned UPPD = (UPP > 0) ? (unsigned)UPP : 1u;   // compile-time divisor
    const unsigned uppv = (UPP > 0) ? (unsigned)UPP : (unsigned)upp;

    const int b   = blockIdx.y;
    const int LoD = Lo * DIM;
    const unsigned n4 = (unsigned)LoD >> 2;
    const long long boff = (long long)b * LoD;

    const f32x4* __restrict__ nz_b    = (const f32x4*)(noise_randn + boff);
    f32x4* __restrict__       sine_b  = (f32x4*)(out_sine + boff);
    f32x4* __restrict__       noise_b = (f32x4*)(out_noise + boff);
    const float*  __restrict__ f0_b   = f0 + b * L;
    const f32x2* __restrict__  rb_b   = rb + b * L * DIM;

    const unsigned tid    = blockIdx.x * blockDim.x + threadIdx.x;
    const unsigned stride = gridDim.x * blockDim.x;

    for (unsigned i4 = tid; i4 < n4; i4 += stride) {
        const unsigned i0 = i4 << 2;
        const f32x4 nr = nz_b[i4];
        unsigned o = i0 / 9u;               // one magic-div per iteration
        unsigned d = i0 - o * 9u;
        f32x4 sv, nv;
        #pragma unroll
        for (int k = 0; k < 4; ++k) {
            unsigned l, j;
            if (UPP > 0) { l = o / UPPD; j = o - l * UPPD; }        // shifts
            else         { l = o / (unsigned)upp; j = o - l * (unsigned)upp; }
            const f32x2 rbv = rb_b[l * 9u + d];     // {rad, base}, L1/L2-hit
            float ph = fmaf((float)(j + 1u), rbv.x, rbv.y);
            ph -= floorf(ph);                        // revolutions in [0,1)
            float s;
            asm("v_sin_f32 %0, %1" : "=v"(s) : "v"(ph));  // sin(2*pi*x)
            const float namp = (rbv.x > 0.0f) ? NOISE_STD : (SINE_AMP / 3.0f);
            const float nzv = namp * nr[k];
            nv[k] = nzv;
            sv[k] = fmaf(s, SINE_AMP, nzv);
            if (k < 3) {                     // incremental (o,d) with wrap
                ++d;
                if (d == 9u) { d = 0u; ++o; }   // compare+select, no branch
            }
        }
        sine_b[i4]  = sv;
        noise_b[i4] = nv;
    }

    // uv output: (B, Lo), fully coalesced float4 stores
    f32x4* __restrict__ uv_b4 = (f32x4*)(out_uv + (long long)b * Lo);
    const unsigned nu4 = (unsigned)Lo >> 2;
    for (unsigned u4 = tid; u4 < nu4; u4 += stride) {
        const unsigned o0 = u4 << 2;
        f32x4 uvv;
        #pragma unroll
        for (int k = 0; k < 4; ++k) {
            const unsigned o = o0 + (unsigned)k;
            const unsigned l = o / uppv;
            uvv[k] = (f0_b[l] > 0.0f) ? 1.0f : 0.0f;
        }
        uv_b4[u4] = uvv;
    }

    // tails (not hit for upp=512; cheap insurance for odd shapes)
    if (blockIdx.x == 0 && threadIdx.x < (unsigned)(LoD & 3)) {
        const unsigned rem = (n4 << 2) + threadIdx.x;
        const unsigned o = rem / 9u;
        const unsigned d = rem - o * 9u;
        const unsigned l = o / uppv;
        const unsigned j = o - l * uppv;
        const f32x2 rbv = rb_b[l * 9u + d];
        float ph = fmaf((float)(j + 1u), rbv.x, rbv.y);
        ph -= floorf(ph);
        float s;
        asm("v_sin_f32 %0, %1" : "=v"(s) : "v"(ph));
        const float namp = (rbv.x > 0.0f) ? NOISE_STD : (SINE_AMP / 3.0f);
        const float nzv = namp * ((const float*)nz_b)[rem];
        ((float*)noise_b)[rem] = nzv;
        ((float*)sine_b)[rem]  = fmaf(s, SINE_AMP, nzv);
    }
    if (blockIdx.x == 0 && threadIdx.x < (unsigned)(Lo & 3)) {
        const unsigned o = (nu4 << 2) + threadIdx.x;
        const unsigned l = o / uppv;
        ((float*)uv_b4)[o] = (f0_b[l] > 0.0f) ? 1.0f : 0.0f;
    }
}

extern "C" void kernel_launch(void* const* d_in, const int* in_sizes, int n_in,
                              void* d_out, int out_size, void* d_ws, size_t ws_size,
                              hipStream_t stream)
{
    const float* f0       = (const float*)d_in[0];
    const float* rand_ini = (const float*)d_in[1];
    const float* noise    = (const float*)d_in[2];
    const int B  = in_sizes[1] / DIM;        // rand_ini is (B, DIM)
    const int L  = in_sizes[0] / B;          // f0 is (B, L)
    const int Lo = in_sizes[2] / (B * DIM);  // noise_randn is (B, Lo, DIM)
    const int upp = Lo / L;

    float* out       = (float*)d_out;
    float* out_sine  = out;
    float* out_uv    = out_sine + (long long)B * Lo * DIM;
    float* out_noise = out_uv + (long long)B * Lo;

    f32x2* rb_ws = (f32x2*)d_ws;

    phase_scan_kernel<<<dim3(B * DIM), dim3(1024), 0, stream>>>(
        f0, rand_ini, rb_ws, B, L, upp);

    const int n4 = (Lo * DIM) >> 2;
    int bx = (n4 + 255) / 256;
    if (bx > 1024) bx = 1024;
    dim3 grid(bx, B);
    if (upp == 512) {
        sine_gen_kernel<512><<<grid, dim3(256), 0, stream>>>(
            f0, noise, rb_ws, out_sine, out_uv, out_noise, L, Lo, upp);
    } else {
        sine_gen_kernel<0><<<grid, dim3(256), 0, stream>>>(
            f0, noise, rb_ws, out_sine, out_uv, out_noise, L, Lo, upp);
    }
}